// Round 1
// 332.932 us; speedup vs baseline: 1.1185x; 1.1185x over previous
//
#include <hip/hip_runtime.h>
#include <math.h>

// Problem constants (from setup_inputs)
#define BB   8
#define CXH  16
#define CXL  8
#define HH   256
#define HL   512

// Tiling
#define TS   32              // 512-res tile edge
#define HALO 2
#define GT   (TS + 2*HALO)   // 36 : LN'd tile + halo
#define GP   38              // padded (even) row pitch for s_gln -> b64-aligned
#define QT   (TS/2)          // 16 : 256-res tile edge
#define DT   (QT + 2)        // 18 : 256-res tile + halo1

// Workspace layout: pre-projected xh, branch-pair interleaved
//   ws[((b*4+br)*HH*HH + iy*HH+ix)*2 + k]   k in {0,1} -> channels 2br, 2br+1
#define WS_PATCH_FLOATS (BB * 4 * HH * HH * 2)     // 4,194,304 floats = 16 MB
#define WS_AB_OFF       WS_PATCH_FLOATS            // A[8], Bc[8] appended
#define WS_NEEDED_BYTES ((size_t)(WS_PATCH_FLOATS + 16) * sizeof(float))

__device__ __forceinline__ float gelu_exact(float x) {
    return 0.5f * x * (1.0f + erff(x * 0.70710678118654752f));
}

// ---------------- Prepass: 1x1 projection 16 -> 8, pair-interleaved ----------------
__global__ __launch_bounds__(256)
void pre_project_kernel(const float* __restrict__ xh,
                        const float* __restrict__ pre_w,
                        const float* __restrict__ pre_b,
                        const float* __restrict__ tail_ln_w,
                        const float* __restrict__ tail_ln_b,
                        const float* __restrict__ tail_w,
                        const float* __restrict__ tail_b,
                        float* __restrict__ ws)
{
    const int gid = blockIdx.x * 256 + threadIdx.x;   // 524288 = 8*256*256
    const int b   = gid >> 16;
    const int px  = gid & 0xFFFF;                     // iy*256+ix
    const float* xp = xh + (b * CXH) * (HH * HH) + px;
    float xv[16];
    #pragma unroll
    for (int c = 0; c < 16; ++c) xv[c] = xp[c * HH * HH];
    #pragma unroll
    for (int br = 0; br < 4; ++br) {
        float a0 = pre_b[2 * br], a1 = pre_b[2 * br + 1];
        #pragma unroll
        for (int c = 0; c < 16; ++c) {
            a0 += pre_w[(2 * br) * 16 + c] * xv[c];
            a1 += pre_w[(2 * br + 1) * 16 + c] * xv[c];
        }
        float2 r; r.x = a0; r.y = a1;
        *(float2*)&ws[((b * 4 + br) * (HH * HH) + px) * 2] = r;
    }
    // One-time: fold tail LN affine into the tail 1x1 (A = tail_w*ln_w rowsum
    // partner, Bc = tail_b + tail_w*ln_b). Saves 320 redundant VALU FMAs per
    // thread in the main kernel.
    if (gid < 8) {
        const int o = gid;
        float a = 0.f, bb = tail_b[o];
        for (int cg = 0; cg < 20; ++cg) {
            a  += tail_w[o * 20 + cg] * tail_ln_w[cg];
            bb += tail_w[o * 20 + cg] * tail_ln_b[cg];
        }
        ws[WS_AB_OFF + o]     = a;
        ws[WS_AB_OFF + 8 + o] = bb;
    }
}

// ---------------- Main fused kernel ----------------
template <bool USE_WS>
__global__ __launch_bounds__(256, 3)
void uem_fused_kernel(const float* __restrict__ xh,
                      const float* __restrict__ xl,
                      const float* __restrict__ mask,
                      const float* __restrict__ pre_w,
                      const float* __restrict__ pre_b,
                      const float* __restrict__ g_ln_w,
                      const float* __restrict__ g_ln_b,
                      const float* __restrict__ g_base_w,
                      const float* __restrict__ g_base_b,
                      const float* __restrict__ g_base_s,
                      const float* __restrict__ g_wt_w,
                      const float* __restrict__ g_wt_s,
                      const float* __restrict__ g_pw_w,
                      const float* __restrict__ tail_ln_w,
                      const float* __restrict__ tail_ln_b,
                      const float* __restrict__ tail_w,
                      const float* __restrict__ tail_b,
                      const float* __restrict__ res_w,
                      const float* __restrict__ res_b,
                      const float* __restrict__ ws,
                      float* __restrict__ out)
{
    // LDS total = 27360 + 25920 = 53280 B  ->  3 blocks/CU (12 waves/CU)
    __shared__ __align__(16) float s_gln[5][GT][GP];   // LN'd branch input (planar, even pitch)
    // Union region: phase0b/1 uses it as xh-patch [20][20][2] (3200 B),
    // phase2/3 as DWT subbands [DT][DT][20] interleaved (25920 B).
    __shared__ __align__(16) float s_un[DT * DT * 20];

    const int b   = blockIdx.z;
    const int ty0 = blockIdx.y * TS;
    const int tx0 = blockIdx.x * TS;
    const int tx  = threadIdx.x, ty = threadIdx.y;
    const int tid = ty * 16 + tx;

    const float SC = (float)(255.0 / 511.0);   // align_corners scale, f32 as in JAX

    const int r0y = max(ty0 - HALO, 0);
    const int r0x = max(tx0 - HALO, 0);
    const int base_iy = min((int)((float)r0y * SC), HH - 20);
    const int base_ix = min((int)((float)r0x * SC), HH - 20);

    // Per-quad-pixel accumulators for tail LN + tail 1x1 pre-products
    float S1[4] = {0.f, 0.f, 0.f, 0.f};
    float S2[4] = {0.f, 0.f, 0.f, 0.f};
    float T[4][8];
    #pragma unroll
    for (int p = 0; p < 4; ++p)
        #pragma unroll
        for (int o = 0; o < 8; ++o) T[p][o] = 0.f;

    for (int br = 0; br < 4; ++br) {
        // ---------- Phase 0b: stage this branch's pre-projected xh patch ----------
        if (USE_WS) {
            const float* wsp = ws + ((b * 4 + br) * (HH * HH)) * 2;
            for (int idx = tid; idx < 400; idx += 256) {
                const int py = idx / 20, px = idx % 20;
                const int iy = base_iy + py, ix = base_ix + px;
                *(float2*)&s_un[idx * 2] = *(const float2*)&wsp[(iy * HH + ix) * 2];
            }
        } else {
            for (int idx = tid; idx < 400; idx += 256) {
                const int py = idx / 20, px = idx % 20;
                const int iy = base_iy + py, ix = base_ix + px;
                const float* xp = xh + ((b * CXH) * HH + iy) * HH + ix;
                float xv[16];
                #pragma unroll
                for (int c = 0; c < 16; ++c) xv[c] = xp[c * HH * HH];
                float2 r;
                float a0 = pre_b[2 * br], a1 = pre_b[2 * br + 1];
                #pragma unroll
                for (int c = 0; c < 16; ++c) {
                    a0 += pre_w[(2 * br) * 16 + c] * xv[c];
                    a1 += pre_w[(2 * br + 1) * 16 + c] * xv[c];
                }
                r.x = a0; r.y = a1;
                *(float2*)&s_un[(py * 20 + px) * 2] = r;
            }
        }
        __syncthreads();

        // ---------- Phase 1: build LN'd gi (tile + halo2) in LDS ----------
        for (int idx = tid; idx < GT * GT; idx += 256) {
            const int ly = idx / GT, lx = idx % GT;
            const int gy = ty0 - HALO + ly, gx = tx0 - HALO + lx;
            float vv[5] = {0.f, 0.f, 0.f, 0.f, 0.f};
            if (gy >= 0 && gy < HL && gx >= 0 && gx < HL) {
                const float cy = (float)gy * SC;
                const int iy0 = min((int)cy, HH - 2);
                const float fy = cy - (float)iy0;
                const float cx = (float)gx * SC;
                const int ix0 = min((int)cx, HH - 2);
                const float fx = cx - (float)ix0;
                const int liy = iy0 - base_iy, lix = ix0 - base_ix;
                const float2 q00 = *(const float2*)&s_un[((liy)     * 20 + lix)     * 2];
                const float2 q01 = *(const float2*)&s_un[((liy)     * 20 + lix + 1) * 2];
                const float2 q10 = *(const float2*)&s_un[((liy + 1) * 20 + lix)     * 2];
                const float2 q11 = *(const float2*)&s_un[((liy + 1) * 20 + lix + 1) * 2];
                {
                    const float top = q00.x + fx * (q01.x - q00.x);
                    const float bot = q10.x + fx * (q11.x - q10.x);
                    vv[0] = top + fy * (bot - top);
                }
                {
                    const float top = q00.y + fx * (q01.y - q00.y);
                    const float bot = q10.y + fx * (q11.y - q10.y);
                    vv[1] = top + fy * (bot - top);
                }
                const int xbase = ((b * CXL) * HL + gy) * HL + gx;
                vv[2] = xl[xbase + (2 * br) * HL * HL];
                vv[3] = xl[xbase + (2 * br + 1) * HL * HL];
                vv[4] = mask[(b * HL + gy) * HL + gx];
                const float u = (vv[0] + vv[1] + vv[2] + vv[3] + vv[4]) * 0.2f;
                float var = 0.f;
                #pragma unroll
                for (int c = 0; c < 5; ++c) { const float d = vv[c] - u; var += d * d; }
                var *= 0.2f;
                const float rstd = rsqrtf(var + 1e-6f);
                #pragma unroll
                for (int c = 0; c < 5; ++c)
                    vv[c] = g_ln_w[br * 5 + c] * ((vv[c] - u) * rstd) + g_ln_b[br * 5 + c];
            }
            #pragma unroll
            for (int c = 0; c < 5; ++c) s_gln[c][ly][lx] = vv[c];
        }
        __syncthreads();

        // ---------- Phase 2: Haar DWT -> channel-interleaved subbands ----------
        for (int idx = tid; idx < DT * DT; idx += 256) {
            const int l = idx / DT, m = idx % DT;
            float* dst = &s_un[(l * DT + m) * 20];
            #pragma unroll
            for (int c = 0; c < 5; ++c) {
                const float2 t0 = *(const float2*)&s_gln[c][2 * l][2 * m];
                const float2 t1 = *(const float2*)&s_gln[c][2 * l + 1][2 * m];
                const float a  = t0.x, b2 = t0.y, c2 = t1.x, d2 = t1.y;
                float4 sb;
                sb.x = 0.5f * (a + b2 + c2 + d2);   // LL
                sb.y = 0.5f * (a + b2 - c2 - d2);   // LH
                sb.z = 0.5f * (a - b2 + c2 - d2);   // HL
                sb.w = 0.5f * (a - b2 - c2 + d2);   // HH
                *(float4*)(dst + c * 4) = sb;
            }
        }
        __syncthreads();

        // ---------- Phase 3: depthwise 3x3 on 20 subbands via b128 reads ----------
        float tag[20];
        #pragma unroll
        for (int j = 0; j < 20; ++j) tag[j] = 0.f;
        const float* wb = g_wt_w + br * 180;
        #pragma unroll
        for (int dy = 0; dy < 3; ++dy) {
            #pragma unroll
            for (int dx = 0; dx < 3; ++dx) {
                const float* p = &s_un[((ty + dy) * DT + (tx + dx)) * 20];
                const float4 v0 = *(const float4*)(p);
                const float4 v1 = *(const float4*)(p + 4);
                const float4 v2 = *(const float4*)(p + 8);
                const float4 v3 = *(const float4*)(p + 12);
                const float4 v4 = *(const float4*)(p + 16);
                const int wo = dy * 3 + dx;
                tag[0]  += wb[0  * 9 + wo] * v0.x;  tag[1]  += wb[1  * 9 + wo] * v0.y;
                tag[2]  += wb[2  * 9 + wo] * v0.z;  tag[3]  += wb[3  * 9 + wo] * v0.w;
                tag[4]  += wb[4  * 9 + wo] * v1.x;  tag[5]  += wb[5  * 9 + wo] * v1.y;
                tag[6]  += wb[6  * 9 + wo] * v1.z;  tag[7]  += wb[7  * 9 + wo] * v1.w;
                tag[8]  += wb[8  * 9 + wo] * v2.x;  tag[9]  += wb[9  * 9 + wo] * v2.y;
                tag[10] += wb[10 * 9 + wo] * v2.z;  tag[11] += wb[11 * 9 + wo] * v2.w;
                tag[12] += wb[12 * 9 + wo] * v3.x;  tag[13] += wb[13 * 9 + wo] * v3.y;
                tag[14] += wb[14 * 9 + wo] * v3.z;  tag[15] += wb[15 * 9 + wo] * v3.w;
                tag[16] += wb[16 * 9 + wo] * v4.x;  tag[17] += wb[17 * 9 + wo] * v4.y;
                tag[18] += wb[18 * 9 + wo] * v4.z;  tag[19] += wb[19 * 9 + wo] * v4.w;
            }
        }
        #pragma unroll
        for (int j = 0; j < 20; ++j) tag[j] *= g_wt_s[br * 20 + j];

        // ---------- IDWT (thread-local 2x2 quad) ----------
        float xt[5][4];
        #pragma unroll
        for (int c = 0; c < 5; ++c) {
            const float LL = tag[c * 4 + 0], LH = tag[c * 4 + 1];
            const float HLv = tag[c * 4 + 2], HHv = tag[c * 4 + 3];
            xt[c][0] = 0.5f * (LL + LH + HLv + HHv);
            xt[c][1] = 0.5f * (LL + LH - HLv - HHv);
            xt[c][2] = 0.5f * (LL - LH + HLv - HHv);
            xt[c][3] = 0.5f * (LL - LH - HLv + HHv);
        }

        // ---------- Phase 4: base 3x3 dwconv via b64 4x6 patches ----------
        float gi[5][4];
        #pragma unroll
        for (int c = 0; c < 5; ++c) {
            float patch[4][6];
            #pragma unroll
            for (int r4 = 0; r4 < 4; ++r4) {
                const float* rp = &s_gln[c][2 * ty + 1 + r4][2 * tx];
                const float2 pa = *(const float2*)(rp);
                const float2 pb = *(const float2*)(rp + 2);
                const float2 pc = *(const float2*)(rp + 4);
                patch[r4][0] = pa.x; patch[r4][1] = pa.y;
                patch[r4][2] = pb.x; patch[r4][3] = pb.y;
                patch[r4][4] = pc.x; patch[r4][5] = pc.y;
            }
            const float* bw = g_base_w + br * 45 + c * 9;
            const float bb2 = g_base_b[br * 5 + c], bs = g_base_s[br * 5 + c];
            #pragma unroll
            for (int p = 0; p < 4; ++p) {
                const int py = p >> 1, px = p & 1;
                float acc = 0.f;
                #pragma unroll
                for (int dy = 0; dy < 3; ++dy)
                    #pragma unroll
                    for (int dx = 0; dx < 3; ++dx)
                        acc += bw[dy * 3 + dx] * patch[py + dy][1 + px + dx];
                gi[c][p] = (acc + bb2) * bs + xt[c][p];
            }
        }

        // ---------- 5x5 pointwise + tail accumulation (tail_w*lw hoisted) ----------
        #pragma unroll
        for (int o = 0; o < 5; ++o) {
            const int cg = br * 5 + o;
            float v[4];
            #pragma unroll
            for (int p = 0; p < 4; ++p) {
                float vv = 0.f;
                #pragma unroll
                for (int c = 0; c < 5; ++c) vv += g_pw_w[br * 25 + o * 5 + c] * gi[c][p];
                v[p] = vv;
                S1[p] += vv;
                S2[p] += vv * vv;
            }
            const float lw = tail_ln_w[cg];
            #pragma unroll
            for (int o8 = 0; o8 < 8; ++o8) {
                const float w = tail_w[o8 * 20 + cg] * lw;
                T[0][o8] += w * v[0];
                T[1][o8] += w * v[1];
                T[2][o8] += w * v[2];
                T[3][o8] += w * v[3];
            }
        }
        __syncthreads();   // before next branch overwrites s_gln / s_un
    }

    // ---------- Phase 5: tail LN (closed form) + 1x1 + GELU + residual ----------
    float A[8], Bc[8];
    if (USE_WS) {
        #pragma unroll
        for (int o = 0; o < 8; ++o) {
            A[o]  = ws[WS_AB_OFF + o];
            Bc[o] = ws[WS_AB_OFF + 8 + o];
        }
    } else {
        #pragma unroll
        for (int o = 0; o < 8; ++o) {
            float a = 0.f, bb = tail_b[o];
            #pragma unroll
            for (int cg = 0; cg < 20; ++cg) {
                a  += tail_w[o * 20 + cg] * tail_ln_w[cg];
                bb += tail_w[o * 20 + cg] * tail_ln_b[cg];
            }
            A[o] = a; Bc[o] = bb;
        }
    }

    #pragma unroll
    for (int py = 0; py < 2; ++py) {
        const int p0 = py * 2, p1 = py * 2 + 1;
        const int gy  = ty0 + 2 * ty + py;
        const int gx0 = tx0 + 2 * tx;
        const float u0    = S1[p0] * 0.05f;
        const float u1    = S1[p1] * 0.05f;
        const float rstd0 = rsqrtf(S2[p0] * 0.05f - u0 * u0 + 1e-6f);
        const float rstd1 = rsqrtf(S2[p1] * 0.05f - u1 * u1 + 1e-6f);

        const int xbase = ((b * CXL) * HL + gy) * HL + gx0;
        float2 xlv[8];
        #pragma unroll
        for (int c = 0; c < 8; ++c) xlv[c] = *(const float2*)&xl[xbase + c * HL * HL];
        const float2 mk = *(const float2*)&mask[(b * HL + gy) * HL + gx0];

        #pragma unroll
        for (int o = 0; o < 8; ++o) {
            const float val0 = (T[p0][o] - u0 * A[o]) * rstd0 + Bc[o];
            const float val1 = (T[p1][o] - u1 * A[o]) * rstd1 + Bc[o];
            float r0 = res_b[o] + res_w[o * 9 + 8] * mk.x;
            float r1 = res_b[o] + res_w[o * 9 + 8] * mk.y;
            #pragma unroll
            for (int c = 0; c < 8; ++c) {
                r0 += res_w[o * 9 + c] * xlv[c].x;
                r1 += res_w[o * 9 + c] * xlv[c].y;
            }
            float2 ov;
            ov.x = gelu_exact(val0) + r0;
            ov.y = gelu_exact(val1) + r1;
            *(float2*)&out[xbase + o * HL * HL] = ov;
        }
    }
}

extern "C" void kernel_launch(void* const* d_in, const int* in_sizes, int n_in,
                              void* d_out, int out_size, void* d_ws, size_t ws_size,
                              hipStream_t stream) {
    (void)in_sizes; (void)out_size;
    if (n_in < 19) return;
    const float* xh        = (const float*)d_in[0];
    const float* xl        = (const float*)d_in[1];
    const float* mask      = (const float*)d_in[2];
    const float* pre_w     = (const float*)d_in[3];
    const float* pre_b     = (const float*)d_in[4];
    const float* g_ln_w    = (const float*)d_in[5];
    const float* g_ln_b    = (const float*)d_in[6];
    const float* g_base_w  = (const float*)d_in[7];
    const float* g_base_b  = (const float*)d_in[8];
    const float* g_base_s  = (const float*)d_in[9];
    const float* g_wt_w    = (const float*)d_in[10];
    const float* g_wt_s    = (const float*)d_in[11];
    const float* g_pw_w    = (const float*)d_in[12];
    const float* tail_ln_w = (const float*)d_in[13];
    const float* tail_ln_b = (const float*)d_in[14];
    const float* tail_w    = (const float*)d_in[15];
    const float* tail_b    = (const float*)d_in[16];
    const float* res_w     = (const float*)d_in[17];
    const float* res_b     = (const float*)d_in[18];
    float* outp = (float*)d_out;
    float* ws   = (float*)d_ws;

    dim3 grid(HL / TS, HL / TS, BB);   // (16, 16, 8) = 2048 blocks
    dim3 block(16, 16, 1);             // 256 threads, each owns a 2x2 output quad

    const bool use_ws = (ws != nullptr) && (ws_size >= WS_NEEDED_BYTES);
    if (use_ws) {
        pre_project_kernel<<<dim3(2048), dim3(256), 0, stream>>>(
            xh, pre_w, pre_b, tail_ln_w, tail_ln_b, tail_w, tail_b, ws);
        uem_fused_kernel<true><<<grid, block, 0, stream>>>(
            xh, xl, mask, pre_w, pre_b, g_ln_w, g_ln_b, g_base_w, g_base_b,
            g_base_s, g_wt_w, g_wt_s, g_pw_w, tail_ln_w, tail_ln_b, tail_w,
            tail_b, res_w, res_b, ws, outp);
    } else {
        uem_fused_kernel<false><<<grid, block, 0, stream>>>(
            xh, xl, mask, pre_w, pre_b, g_ln_w, g_ln_b, g_base_w, g_base_b,
            g_base_s, g_wt_w, g_wt_s, g_pw_w, tail_ln_w, tail_ln_b, tail_w,
            tail_b, res_w, res_b, ws, outp);
    }
}